// Round 1
// baseline (13167.900 us; speedup 1.0000x reference)
//
#include <hip/hip_runtime.h>
#include <math.h>

typedef unsigned short u16;
typedef unsigned int u32;
#define DEVI __device__ __forceinline__

// problem constants
constexpr int kB = 2, kC = 96, kD = 32, kH = 64, kW = 64;
constexpr int kS = kD * kH * kW;   // 131072 spatial positions per batch
constexpr int kM = kB * kS;        // 262144 total tokens
constexpr int kBW = 4096;          // total windows (2 batches * 8*16*16)
constexpr float kScale = 0.17677669529663687f;  // 32^-0.5

DEVI u16 f2bf(float f) {           // fp32 -> bf16 round-to-nearest-even
  u32 x = __float_as_uint(f);
  return (u16)((x + 0x7fffu + ((x >> 16) & 1u)) >> 16);
}
DEVI float bf2f(u16 v) { return __uint_as_float(((u32)v) << 16); }
DEVI u32 pack2(float a, float b) { return (u32)f2bf(a) | ((u32)f2bf(b) << 16); }

// ---------------- transpose (B,C,S) <-> (B,S,C) ----------------
__global__ void k_tin(const float* __restrict__ in, float* __restrict__ out) {
  __shared__ float tile[32][33];
  int s0 = blockIdx.x << 5, c0 = blockIdx.y << 5, b = blockIdx.z;
  int tx = threadIdx.x, ty = threadIdx.y;
#pragma unroll
  for (int q = 0; q < 4; q++)
    tile[ty + q * 8][tx] = in[((size_t)(b * kC + c0 + ty + q * 8)) * kS + s0 + tx];
  __syncthreads();
#pragma unroll
  for (int q = 0; q < 4; q++)
    out[((size_t)(b * kS + s0 + ty + q * 8)) * kC + c0 + tx] = tile[tx][ty + q * 8];
}

__global__ void k_tout(const float* __restrict__ in, float* __restrict__ out) {
  __shared__ float tile[32][33];
  int s0 = blockIdx.x << 5, c0 = blockIdx.y << 5, b = blockIdx.z;
  int tx = threadIdx.x, ty = threadIdx.y;
#pragma unroll
  for (int q = 0; q < 4; q++)
    tile[ty + q * 8][tx] = in[((size_t)(b * kS + s0 + ty + q * 8)) * kC + c0 + tx];
  __syncthreads();
#pragma unroll
  for (int q = 0; q < 4; q++)
    out[((size_t)(b * kC + c0 + ty + q * 8)) * kS + s0 + tx] = tile[tx][ty + q * 8];
}

// ---------------- LayerNorm (one wave per 96-channel row) ----------------
// MODE 0: natural row order. MODE 1: window-partition output order.
// MODE 2: window-partition of the (-2,-2,-2)-rolled tensor.
template <int MODE>
__global__ __launch_bounds__(256) void k_ln(const float* __restrict__ x,
                                            const float* __restrict__ g,
                                            const float* __restrict__ bt,
                                            u16* __restrict__ out) {
  int row = (blockIdx.x << 2) + (threadIdx.x >> 6);
  int lane = threadIdx.x & 63;
  int src;
  if (MODE == 0) {
    src = row;
  } else {
    int widx = row >> 6, n = row & 63;
    int ww = widx & 15, wh = (widx >> 4) & 15, wd = (widx >> 8) & 7, bb = widx >> 11;
    int lw = n & 3, lh = (n >> 2) & 3, ld = n >> 4;
    int d = wd * 4 + ld, h = wh * 4 + lh, w = ww * 4 + lw;
    if (MODE == 2) { d = (d + 2) & 31; h = (h + 2) & 63; w = (w + 2) & 63; }
    src = ((bb * kD + d) * kH + h) * kW + w;
  }
  const float* xr = x + (size_t)src * kC;
  float a0 = xr[lane];
  float a1 = (lane < 32) ? xr[64 + lane] : 0.f;
  float sum = a0 + a1;
#pragma unroll
  for (int m = 32; m; m >>= 1) sum += __shfl_xor(sum, m);
  float mean = sum * (1.f / 96.f);
  float d0 = a0 - mean, d1 = (lane < 32) ? a1 - mean : 0.f;
  float vs = d0 * d0 + d1 * d1;
#pragma unroll
  for (int m = 32; m; m >>= 1) vs += __shfl_xor(vs, m);
  float rstd = rsqrtf(vs * (1.f / 96.f) + 1e-5f);
  u16* orow = out + (size_t)row * kC;
  orow[lane] = f2bf(d0 * rstd * g[lane] + bt[lane]);
  if (lane < 32) orow[64 + lane] = f2bf(d1 * rstd * g[64 + lane] + bt[64 + lane]);
}

// ---------------- generic skinny-K GEMM: out[r][j] = sum_k X[r][k]*W[j][k]+b[j]
// 64 rows x 96 cols per block, K in chunks of 96. X bf16, W fp32 (LDS-staged).
// EPI 0: bf16 store. EPI 1: GELU -> bf16 store. EPI 2: fp32 += into oadd (residual).
// GATHER 1: X row index = window-partition source of natural row r (proj epilogue path).
template <int KTOT, int EPI, int GATHER>
__global__ __launch_bounds__(256) void k_gemm(const u16* __restrict__ X,
                                              const float* __restrict__ Wm,
                                              const float* __restrict__ bias,
                                              u16* __restrict__ obf,
                                              float* __restrict__ oadd,
                                              int njtot, int shifted) {
  __shared__ __align__(16) u16 Xs[64 * 104];
  __shared__ __align__(16) float Ws[96 * 100];
  int tid = threadIdx.x;
  int tx = tid & 15, ty = tid >> 4;
  int r0 = blockIdx.x << 6;
  int j0 = blockIdx.y * 96;
  float acc[4][6];
#pragma unroll
  for (int i = 0; i < 4; i++)
#pragma unroll
    for (int j = 0; j < 6; j++) acc[i][j] = 0.f;

  for (int kc = 0; kc < KTOT; kc += 96) {
    if (kc) __syncthreads();
    // stage 64x96 activation tile (bf16, row stride padded to 104)
    for (int slot = tid; slot < 64 * 12; slot += 256) {
      int row = slot / 12, c8 = slot % 12;
      int r = r0 + row, rsrc;
      if (GATHER) {
        int w = r & 63, h = (r >> 6) & 63, d = (r >> 12) & 31, bb = r >> 17;
        if (shifted) { d = (d + 30) & 31; h = (h + 62) & 63; w = (w + 62) & 63; }
        int widx = ((bb * 8 + (d >> 2)) * 16 + (h >> 2)) * 16 + (w >> 2);
        rsrc = (widx << 6) + ((d & 3) << 4) + ((h & 3) << 2) + (w & 3);
      } else {
        rsrc = r;
      }
      *(uint4*)&Xs[row * 104 + c8 * 8] =
          *(const uint4*)(X + (size_t)rsrc * KTOT + kc + c8 * 8);
    }
    // stage 96x96 weight tile (fp32, row stride padded to 100)
    for (int slot = tid; slot < 96 * 12; slot += 256) {
      int row = slot / 12, c8 = slot % 12;
      const float4* s = (const float4*)(Wm + (size_t)(j0 + row) * KTOT + kc + c8 * 8);
      float* dst = &Ws[row * 100 + c8 * 8];
      *(float4*)dst = s[0];
      *(float4*)(dst + 4) = s[1];
    }
    __syncthreads();
#pragma unroll
    for (int k8 = 0; k8 < 12; k8++) {
      float xf[4][8];
#pragma unroll
      for (int i = 0; i < 4; i++) {
        uint4 v = *(const uint4*)&Xs[(ty * 4 + i) * 104 + k8 * 8];
        xf[i][0] = __uint_as_float(v.x << 16); xf[i][1] = __uint_as_float(v.x & 0xffff0000u);
        xf[i][2] = __uint_as_float(v.y << 16); xf[i][3] = __uint_as_float(v.y & 0xffff0000u);
        xf[i][4] = __uint_as_float(v.z << 16); xf[i][5] = __uint_as_float(v.z & 0xffff0000u);
        xf[i][6] = __uint_as_float(v.w << 16); xf[i][7] = __uint_as_float(v.w & 0xffff0000u);
      }
#pragma unroll
      for (int j = 0; j < 6; j++) {
        const float* wr = &Ws[(tx + 16 * j) * 100 + k8 * 8];
        float4 w0 = *(const float4*)wr, w1 = *(const float4*)(wr + 4);
        float wf[8] = {w0.x, w0.y, w0.z, w0.w, w1.x, w1.y, w1.z, w1.w};
#pragma unroll
        for (int e = 0; e < 8; e++)
#pragma unroll
          for (int i = 0; i < 4; i++)
            acc[i][j] = fmaf(xf[i][e], wf[e], acc[i][j]);
      }
    }
  }
#pragma unroll
  for (int i = 0; i < 4; i++) {
    int r = r0 + ty * 4 + i;
#pragma unroll
    for (int jj = 0; jj < 6; jj++) {
      int j = j0 + tx + 16 * jj;
      float v = acc[i][jj] + bias[j];
      if (EPI == 0) {
        obf[(size_t)r * njtot + j] = f2bf(v);
      } else if (EPI == 1) {
        obf[(size_t)r * njtot + j] = f2bf(0.5f * v * (1.f + erff(v * 0.70710678118654752f)));
      } else {
        oadd[(size_t)r * 96 + j] += v;
      }
    }
  }
}

// ---------------- windowed attention: one block per (window, head) ----------
__global__ __launch_bounds__(256) void k_attn(const u16* __restrict__ qkv,
                                              const float* __restrict__ rpb,
                                              u16* __restrict__ out, int shifted) {
  __shared__ __align__(16) float q[64][36];
  __shared__ __align__(16) float kk[64][36];
  __shared__ __align__(16) float vv[64][32];
  __shared__ float p[64][66];
  __shared__ float rpbs[343];
  int widx = blockIdx.x, h = blockIdx.y;
  int tid = threadIdx.x;
  for (int t = tid; t < 343; t += 256) rpbs[t] = rpb[t * 3 + h];
  size_t base = (size_t)widx * 64 * 288 + h * 32;
  for (int idx = tid; idx < 2048; idx += 256) {
    int n = idx >> 5, d = idx & 31;
    size_t o = base + (size_t)n * 288 + d;
    q[n][d] = bf2f(qkv[o]) * kScale;
    kk[n][d] = bf2f(qkv[o + 96]);
    vv[n][d] = bf2f(qkv[o + 192]);
  }
  __syncthreads();

  int i = tid >> 2, jg = tid & 3;
  int ld = i >> 4, lh = (i >> 2) & 3, lw = i & 3;
  int ww = widx & 15, wh = (widx >> 4) & 15, wd = (widx >> 8) & 7;
  int cnti = 0;
  if (shifted)
    cnti = ((wd == 7) ? (1 + (ld >= 2)) : 0) * 9 +
           ((wh == 15) ? (1 + (lh >= 2)) : 0) * 3 +
           ((ww == 15) ? (1 + (lw >= 2)) : 0);
  float qr[32];
#pragma unroll
  for (int d4 = 0; d4 < 8; d4++) {
    float4 t = *(const float4*)&q[i][d4 * 4];
    qr[d4 * 4] = t.x; qr[d4 * 4 + 1] = t.y; qr[d4 * 4 + 2] = t.z; qr[d4 * 4 + 3] = t.w;
  }
  float s[16];
#pragma unroll
  for (int jj = 0; jj < 16; jj++) {
    int j = jg * 16 + jj;
    float a = 0.f;
#pragma unroll
    for (int d4 = 0; d4 < 8; d4++) {
      float4 kv = *(const float4*)&kk[j][d4 * 4];
      a = fmaf(qr[d4 * 4], kv.x, a);
      a = fmaf(qr[d4 * 4 + 1], kv.y, a);
      a = fmaf(qr[d4 * 4 + 2], kv.z, a);
      a = fmaf(qr[d4 * 4 + 3], kv.w, a);
    }
    int jd = j >> 4, jh = (j >> 2) & 3, jw = j & 3;
    a += rpbs[(ld - jd + 3) * 49 + (lh - jh + 3) * 7 + (lw - jw + 3)];
    if (shifted) {
      int cntj = ((wd == 7) ? (1 + (jd >= 2)) : 0) * 9 +
                 ((wh == 15) ? (1 + (jh >= 2)) : 0) * 3 +
                 ((ww == 15) ? (1 + (jw >= 2)) : 0);
      if (cntj != cnti) a -= 100.f;
    }
    s[jj] = a;
  }
  float mx = s[0];
#pragma unroll
  for (int jj = 1; jj < 16; jj++) mx = fmaxf(mx, s[jj]);
  mx = fmaxf(mx, __shfl_xor(mx, 1));
  mx = fmaxf(mx, __shfl_xor(mx, 2));
  float sum = 0.f;
#pragma unroll
  for (int jj = 0; jj < 16; jj++) { s[jj] = __expf(s[jj] - mx); sum += s[jj]; }
  sum += __shfl_xor(sum, 1);
  sum += __shfl_xor(sum, 2);
  float inv = 1.f / sum;
#pragma unroll
  for (int jj = 0; jj < 16; jj++) p[i][jg * 16 + jj] = s[jj] * inv;
  __syncthreads();

  // PV: thread (i, dg) computes out[i][dg*8 .. dg*8+7]
  int dg = jg;
  float acc[8];
#pragma unroll
  for (int e = 0; e < 8; e++) acc[e] = 0.f;
  for (int j = 0; j < 64; j++) {
    float pf = p[i][j];
    const float4* vp = (const float4*)&vv[j][dg * 8];
    float4 v0 = vp[0], v1 = vp[1];
    acc[0] = fmaf(pf, v0.x, acc[0]); acc[1] = fmaf(pf, v0.y, acc[1]);
    acc[2] = fmaf(pf, v0.z, acc[2]); acc[3] = fmaf(pf, v0.w, acc[3]);
    acc[4] = fmaf(pf, v1.x, acc[4]); acc[5] = fmaf(pf, v1.y, acc[5]);
    acc[6] = fmaf(pf, v1.z, acc[6]); acc[7] = fmaf(pf, v1.w, acc[7]);
  }
  uint4 o4 = {pack2(acc[0], acc[1]), pack2(acc[2], acc[3]),
              pack2(acc[4], acc[5]), pack2(acc[6], acc[7])};
  *(uint4*)(out + ((size_t)(widx * 64 + i) * 96 + h * 32 + dg * 8)) = o4;
}

// ---------------- launcher ----------------
extern "C" void kernel_launch(void* const* d_in, const int* in_sizes, int n_in,
                              void* d_out, int out_size, void* d_ws, size_t ws_size,
                              hipStream_t stream) {
  const float* x_in = (const float*)d_in[0];
  const float* n1g = (const float*)d_in[1];
  const float* n1b = (const float*)d_in[2];
  const float* qkvw = (const float*)d_in[3];
  const float* qkvb = (const float*)d_in[4];
  const float* rpb = (const float*)d_in[5];
  const float* projw = (const float*)d_in[6];
  const float* projb = (const float*)d_in[7];
  const float* n2g = (const float*)d_in[8];
  const float* n2b = (const float*)d_in[9];
  const float* fc1w = (const float*)d_in[10];
  const float* fc1b = (const float*)d_in[11];
  const float* fc2w = (const float*)d_in[12];
  const float* fc2b = (const float*)d_in[13];
  float* outp = (float*)d_out;

  // workspace: fp32 master x (100.7 MB) | bf16 small buf (50.3 MB) | bf16 big buf (201.3 MB)
  char* ws = (char*)d_ws;
  float* bx = (float*)ws;
  u16* ba = (u16*)(ws + 100663296);   // xw / attn_out / xn2
  u16* bb = (u16*)(ws + 150994944);   // qkv / mlp hidden

  k_tin<<<dim3(kS / 32, 3, kB), dim3(32, 8), 0, stream>>>(x_in, bx);

  for (int blk = 0; blk < 2; blk++) {
    int sh = blk;  // block 1 is shifted
    if (blk == 0)
      k_ln<1><<<kM / 4, 256, 0, stream>>>(bx, n1g, n1b, ba);
    else
      k_ln<2><<<kM / 4, 256, 0, stream>>>(bx, n1g + 96, n1b + 96, ba);
    k_gemm<96, 0, 0><<<dim3(kM / 64, 3), 256, 0, stream>>>(
        ba, qkvw + blk * 288 * 96, qkvb + blk * 288, bb, nullptr, 288, 0);
    k_attn<<<dim3(kBW, 3), 256, 0, stream>>>(bb, rpb + blk * 343 * 3, ba, sh);
    k_gemm<96, 2, 1><<<dim3(kM / 64, 1), 256, 0, stream>>>(
        ba, projw + blk * 96 * 96, projb + blk * 96, nullptr, bx, 96, sh);
    k_ln<0><<<kM / 4, 256, 0, stream>>>(bx, n2g + blk * 96, n2b + blk * 96, ba);
    k_gemm<96, 1, 0><<<dim3(kM / 64, 4), 256, 0, stream>>>(
        ba, fc1w + blk * 384 * 96, fc1b + blk * 384, bb, nullptr, 384, 0);
    k_gemm<384, 2, 0><<<dim3(kM / 64, 1), 256, 0, stream>>>(
        bb, fc2w + blk * 96 * 384, fc2b + blk * 96, nullptr, bx, 96, 0);
  }

  k_tout<<<dim3(kS / 32, 3, kB), dim3(32, 8), 0, stream>>>(bx, outp);
}

// Round 2
// 1513.509 us; speedup vs baseline: 8.7002x; 8.7002x over previous
//
#include <hip/hip_runtime.h>
#include <math.h>

typedef unsigned short u16;
typedef unsigned int u32;
#define DEVI __device__ __forceinline__

typedef __attribute__((ext_vector_type(8))) short bf16x8;
typedef __attribute__((ext_vector_type(4))) float f32x4;

// problem constants
constexpr int kB = 2, kC = 96, kD = 32, kH = 64, kW = 64;
constexpr int kS = kD * kH * kW;   // 131072 spatial positions per batch
constexpr int kM = kB * kS;        // 262144 total tokens
constexpr int kBW = 4096;          // total windows
constexpr float kScale = 0.17677669529663687f;  // 32^-0.5

DEVI u16 f2bf(float f) {           // fp32 -> bf16 round-to-nearest-even
  u32 x = __float_as_uint(f);
  return (u16)((x + 0x7fffu + ((x >> 16) & 1u)) >> 16);
}
DEVI float bf2f(u16 v) { return __uint_as_float(((u32)v) << 16); }
DEVI u32 pack2(float a, float b) { return (u32)f2bf(a) | ((u32)f2bf(b) << 16); }

// ---------------- transpose (B,C,S) <-> (B,S,C) ----------------
__global__ void k_tin(const float* __restrict__ in, float* __restrict__ out) {
  __shared__ float tile[32][33];
  int s0 = blockIdx.x << 5, c0 = blockIdx.y << 5, b = blockIdx.z;
  int tx = threadIdx.x, ty = threadIdx.y;
#pragma unroll
  for (int q = 0; q < 4; q++)
    tile[ty + q * 8][tx] = in[((size_t)(b * kC + c0 + ty + q * 8)) * kS + s0 + tx];
  __syncthreads();
#pragma unroll
  for (int q = 0; q < 4; q++)
    out[((size_t)(b * kS + s0 + ty + q * 8)) * kC + c0 + tx] = tile[tx][ty + q * 8];
}

__global__ void k_tout(const float* __restrict__ in, float* __restrict__ out) {
  __shared__ float tile[32][33];
  int s0 = blockIdx.x << 5, c0 = blockIdx.y << 5, b = blockIdx.z;
  int tx = threadIdx.x, ty = threadIdx.y;
#pragma unroll
  for (int q = 0; q < 4; q++)
    tile[ty + q * 8][tx] = in[((size_t)(b * kS + s0 + ty + q * 8)) * kC + c0 + tx];
  __syncthreads();
#pragma unroll
  for (int q = 0; q < 4; q++)
    out[((size_t)(b * kC + c0 + ty + q * 8)) * kS + s0 + tx] = tile[tx][ty + q * 8];
}

// ---------------- LayerNorm (one wave per 96-channel row) ----------------
template <int MODE>
__global__ __launch_bounds__(256) void k_ln(const float* __restrict__ x,
                                            const float* __restrict__ g,
                                            const float* __restrict__ bt,
                                            u16* __restrict__ out) {
  int row = (blockIdx.x << 2) + (threadIdx.x >> 6);
  int lane = threadIdx.x & 63;
  int src;
  if (MODE == 0) {
    src = row;
  } else {
    int widx = row >> 6, n = row & 63;
    int ww = widx & 15, wh = (widx >> 4) & 15, wd = (widx >> 8) & 7, bb = widx >> 11;
    int lw = n & 3, lh = (n >> 2) & 3, ld = n >> 4;
    int d = wd * 4 + ld, h = wh * 4 + lh, w = ww * 4 + lw;
    if (MODE == 2) { d = (d + 2) & 31; h = (h + 2) & 63; w = (w + 2) & 63; }
    src = ((bb * kD + d) * kH + h) * kW + w;
  }
  const float* xr = x + (size_t)src * kC;
  float a0 = xr[lane];
  float a1 = (lane < 32) ? xr[64 + lane] : 0.f;
  float sum = a0 + a1;
#pragma unroll
  for (int m = 32; m; m >>= 1) sum += __shfl_xor(sum, m);
  float mean = sum * (1.f / 96.f);
  float d0 = a0 - mean, d1 = (lane < 32) ? a1 - mean : 0.f;
  float vs = d0 * d0 + d1 * d1;
#pragma unroll
  for (int m = 32; m; m >>= 1) vs += __shfl_xor(vs, m);
  float rstd = rsqrtf(vs * (1.f / 96.f) + 1e-5f);
  u16* orow = out + (size_t)row * kC;
  orow[lane] = f2bf(d0 * rstd * g[lane] + bt[lane]);
  if (lane < 32) orow[64 + lane] = f2bf(d1 * rstd * g[64 + lane] + bt[64 + lane]);
}

// ---------------- MFMA GEMM: out[r][j] = sum_k X[r][k]*W[j][k] + b[j] -------
// Block = 128 rows x 96 cols. 4 waves, each 32 rows x 96 cols (2x6 frags).
// X bf16 [M][KTOT]; W fp32 [N][KTOT] (converted to bf16 during LDS staging).
// EPI 0: bf16 store. EPI 1: GELU -> bf16. EPI 2: fp32 += into oadd (residual).
// GATHER 1: X row = window-partition source of natural row r (proj path).
template <int KTOT, int EPI, int GATHER>
__global__ __launch_bounds__(256) void k_mm(const u16* __restrict__ X,
                                            const float* __restrict__ Wm,
                                            const float* __restrict__ bias,
                                            u16* __restrict__ obf,
                                            float* __restrict__ oadd,
                                            int njtot, int shifted) {
  __shared__ __align__(16) u16 Xs[128][104];
  __shared__ __align__(16) u16 Ws[96][104];
  int tid = threadIdx.x;
  int wv = tid >> 6, lane = tid & 63;
  int llo = lane & 15, lhi = lane >> 4;
  int r0 = blockIdx.x << 7;
  int j0 = blockIdx.y * 96;
  f32x4 acc[2][6];
#pragma unroll
  for (int i = 0; i < 2; i++)
#pragma unroll
    for (int j = 0; j < 6; j++) acc[i][j] = (f32x4){0.f, 0.f, 0.f, 0.f};

  for (int kc = 0; kc < KTOT; kc += 96) {
    if (kc) __syncthreads();
    // stage 128x96 activation tile (bf16, row stride padded to 104)
    for (int s = tid; s < 128 * 12; s += 256) {
      int row = s / 12, c8 = s - row * 12;
      int r = r0 + row, rsrc;
      if (GATHER) {
        int w = r & 63, h = (r >> 6) & 63, d = (r >> 12) & 31, bb = r >> 17;
        if (shifted) { d = (d + 30) & 31; h = (h + 62) & 63; w = (w + 62) & 63; }
        int widx = ((bb * 8 + (d >> 2)) * 16 + (h >> 2)) * 16 + (w >> 2);
        rsrc = (widx << 6) + ((d & 3) << 4) + ((h & 3) << 2) + (w & 3);
      } else {
        rsrc = r;
      }
      *(uint4*)&Xs[row][c8 * 8] = *(const uint4*)(X + (size_t)rsrc * KTOT + kc + c8 * 8);
    }
    // stage 96x96 weight tile, fp32 -> bf16
    for (int s = tid; s < 96 * 12; s += 256) {
      int row = s / 12, c8 = s - row * 12;
      const float* src = Wm + (size_t)(j0 + row) * KTOT + kc + c8 * 8;
      float4 w0 = *(const float4*)src, w1 = *(const float4*)(src + 4);
      uint4 pk = {pack2(w0.x, w0.y), pack2(w0.z, w0.w),
                  pack2(w1.x, w1.y), pack2(w1.z, w1.w)};
      *(uint4*)&Ws[row][c8 * 8] = pk;
    }
    __syncthreads();
#pragma unroll
    for (int ks = 0; ks < 3; ks++) {
      bf16x8 a[2], b[6];
#pragma unroll
      for (int i = 0; i < 2; i++)
        a[i] = *(const bf16x8*)&Xs[wv * 32 + i * 16 + llo][ks * 32 + lhi * 8];
#pragma unroll
      for (int j = 0; j < 6; j++)
        b[j] = *(const bf16x8*)&Ws[j * 16 + llo][ks * 32 + lhi * 8];
#pragma unroll
      for (int i = 0; i < 2; i++)
#pragma unroll
        for (int j = 0; j < 6; j++)
          acc[i][j] = __builtin_amdgcn_mfma_f32_16x16x32_bf16(a[i], b[j], acc[i][j], 0, 0, 0);
    }
  }
  // epilogue: D layout col = lane&15, row = (lane>>4)*4 + reg   [m89]
#pragma unroll
  for (int i = 0; i < 2; i++) {
    int rbase = r0 + wv * 32 + i * 16 + lhi * 4;
#pragma unroll
    for (int j = 0; j < 6; j++) {
      int col = j0 + j * 16 + llo;
      float bv = bias[col];
#pragma unroll
      for (int rg = 0; rg < 4; rg++) {
        float v = acc[i][j][rg] + bv;
        int row = rbase + rg;
        if (EPI == 0) {
          obf[(size_t)row * njtot + col] = f2bf(v);
        } else if (EPI == 1) {
          obf[(size_t)row * njtot + col] =
              f2bf(0.5f * v * (1.f + erff(v * 0.70710678118654752f)));
        } else {
          oadd[(size_t)row * 96 + col] += v;
        }
      }
    }
  }
}

// ---------------- windowed attention: one block per (window, head) ----------
__global__ __launch_bounds__(256) void k_attn(const u16* __restrict__ qkv,
                                              const float* __restrict__ rpb,
                                              u16* __restrict__ out, int shifted) {
  __shared__ __align__(16) float q[64][36];
  __shared__ __align__(16) float kk[64][36];
  __shared__ __align__(16) float vv[64][32];
  __shared__ float p[64][66];
  __shared__ float rpbs[343];
  int widx = blockIdx.x, h = blockIdx.y;
  int tid = threadIdx.x;
  for (int t = tid; t < 343; t += 256) rpbs[t] = rpb[t * 3 + h];
  size_t base = (size_t)widx * 64 * 288 + h * 32;
  for (int idx = tid; idx < 2048; idx += 256) {
    int n = idx >> 5, d = idx & 31;
    size_t o = base + (size_t)n * 288 + d;
    q[n][d] = bf2f(qkv[o]) * kScale;
    kk[n][d] = bf2f(qkv[o + 96]);
    vv[n][d] = bf2f(qkv[o + 192]);
  }
  __syncthreads();

  int i = tid >> 2, jg = tid & 3;
  int ld = i >> 4, lh = (i >> 2) & 3, lw = i & 3;
  int ww = widx & 15, wh = (widx >> 4) & 15, wd = (widx >> 8) & 7;
  int cnti = 0;
  if (shifted)
    cnti = ((wd == 7) ? (1 + (ld >= 2)) : 0) * 9 +
           ((wh == 15) ? (1 + (lh >= 2)) : 0) * 3 +
           ((ww == 15) ? (1 + (lw >= 2)) : 0);
  float qr[32];
#pragma unroll
  for (int d4 = 0; d4 < 8; d4++) {
    float4 t = *(const float4*)&q[i][d4 * 4];
    qr[d4 * 4] = t.x; qr[d4 * 4 + 1] = t.y; qr[d4 * 4 + 2] = t.z; qr[d4 * 4 + 3] = t.w;
  }
  float s[16];
#pragma unroll
  for (int jj = 0; jj < 16; jj++) {
    int j = jg * 16 + jj;
    float a = 0.f;
#pragma unroll
    for (int d4 = 0; d4 < 8; d4++) {
      float4 kv = *(const float4*)&kk[j][d4 * 4];
      a = fmaf(qr[d4 * 4], kv.x, a);
      a = fmaf(qr[d4 * 4 + 1], kv.y, a);
      a = fmaf(qr[d4 * 4 + 2], kv.z, a);
      a = fmaf(qr[d4 * 4 + 3], kv.w, a);
    }
    int jd = j >> 4, jh = (j >> 2) & 3, jw = j & 3;
    a += rpbs[(ld - jd + 3) * 49 + (lh - jh + 3) * 7 + (lw - jw + 3)];
    if (shifted) {
      int cntj = ((wd == 7) ? (1 + (jd >= 2)) : 0) * 9 +
                 ((wh == 15) ? (1 + (jh >= 2)) : 0) * 3 +
                 ((ww == 15) ? (1 + (jw >= 2)) : 0);
      if (cntj != cnti) a -= 100.f;
    }
    s[jj] = a;
  }
  float mx = s[0];
#pragma unroll
  for (int jj = 1; jj < 16; jj++) mx = fmaxf(mx, s[jj]);
  mx = fmaxf(mx, __shfl_xor(mx, 1));
  mx = fmaxf(mx, __shfl_xor(mx, 2));
  float sum = 0.f;
#pragma unroll
  for (int jj = 0; jj < 16; jj++) { s[jj] = __expf(s[jj] - mx); sum += s[jj]; }
  sum += __shfl_xor(sum, 1);
  sum += __shfl_xor(sum, 2);
  float inv = 1.f / sum;
#pragma unroll
  for (int jj = 0; jj < 16; jj++) p[i][jg * 16 + jj] = s[jj] * inv;
  __syncthreads();

  int dg = jg;
  float acc[8];
#pragma unroll
  for (int e = 0; e < 8; e++) acc[e] = 0.f;
  for (int j = 0; j < 64; j++) {
    float pf = p[i][j];
    const float4* vp = (const float4*)&vv[j][dg * 8];
    float4 v0 = vp[0], v1 = vp[1];
    acc[0] = fmaf(pf, v0.x, acc[0]); acc[1] = fmaf(pf, v0.y, acc[1]);
    acc[2] = fmaf(pf, v0.z, acc[2]); acc[3] = fmaf(pf, v0.w, acc[3]);
    acc[4] = fmaf(pf, v1.x, acc[4]); acc[5] = fmaf(pf, v1.y, acc[5]);
    acc[6] = fmaf(pf, v1.z, acc[6]); acc[7] = fmaf(pf, v1.w, acc[7]);
  }
  uint4 o4 = {pack2(acc[0], acc[1]), pack2(acc[2], acc[3]),
              pack2(acc[4], acc[5]), pack2(acc[6], acc[7])};
  *(uint4*)(out + ((size_t)(widx * 64 + i) * 96 + h * 32 + dg * 8)) = o4;
}

// ---------------- launcher ----------------
extern "C" void kernel_launch(void* const* d_in, const int* in_sizes, int n_in,
                              void* d_out, int out_size, void* d_ws, size_t ws_size,
                              hipStream_t stream) {
  const float* x_in = (const float*)d_in[0];
  const float* n1g = (const float*)d_in[1];
  const float* n1b = (const float*)d_in[2];
  const float* qkvw = (const float*)d_in[3];
  const float* qkvb = (const float*)d_in[4];
  const float* rpb = (const float*)d_in[5];
  const float* projw = (const float*)d_in[6];
  const float* projb = (const float*)d_in[7];
  const float* n2g = (const float*)d_in[8];
  const float* n2b = (const float*)d_in[9];
  const float* fc1w = (const float*)d_in[10];
  const float* fc1b = (const float*)d_in[11];
  const float* fc2w = (const float*)d_in[12];
  const float* fc2b = (const float*)d_in[13];
  float* outp = (float*)d_out;

  // workspace: fp32 master x (100.7 MB) | bf16 small buf (50.3 MB) | bf16 big buf (201.3 MB)
  char* ws = (char*)d_ws;
  float* bx = (float*)ws;
  u16* ba = (u16*)(ws + 100663296);   // xw / attn_out / xn2
  u16* bb = (u16*)(ws + 150994944);   // qkv / mlp hidden

  k_tin<<<dim3(kS / 32, 3, kB), dim3(32, 8), 0, stream>>>(x_in, bx);

  for (int blk = 0; blk < 2; blk++) {
    int sh = blk;  // block 1 is shifted
    if (blk == 0)
      k_ln<1><<<kM / 4, 256, 0, stream>>>(bx, n1g, n1b, ba);
    else
      k_ln<2><<<kM / 4, 256, 0, stream>>>(bx, n1g + 96, n1b + 96, ba);
    k_mm<96, 0, 0><<<dim3(kM / 128, 3), 256, 0, stream>>>(
        ba, qkvw + blk * 288 * 96, qkvb + blk * 288, bb, nullptr, 288, 0);
    k_attn<<<dim3(kBW, 3), 256, 0, stream>>>(bb, rpb + blk * 343 * 3, ba, sh);
    k_mm<96, 2, 1><<<dim3(kM / 128, 1), 256, 0, stream>>>(
        ba, projw + blk * 96 * 96, projb + blk * 96, nullptr, bx, 96, sh);
    k_ln<0><<<kM / 4, 256, 0, stream>>>(bx, n2g + blk * 96, n2b + blk * 96, ba);
    k_mm<96, 1, 0><<<dim3(kM / 128, 4), 256, 0, stream>>>(
        ba, fc1w + blk * 384 * 96, fc1b + blk * 384, bb, nullptr, 384, 0);
    k_mm<384, 2, 0><<<dim3(kM / 128, 1), 256, 0, stream>>>(
        bb, fc2w + blk * 96 * 384, fc2b + blk * 96, nullptr, bx, 96, 0);
  }

  k_tout<<<dim3(kS / 32, 3, kB), dim3(32, 8), 0, stream>>>(bx, outp);
}

// Round 3
// 1097.029 us; speedup vs baseline: 12.0032x; 1.3796x over previous
//
#include <hip/hip_runtime.h>
#include <math.h>

typedef unsigned short u16;
typedef unsigned int u32;
#define DEVI __device__ __forceinline__

typedef __attribute__((ext_vector_type(8))) short bf16x8;
typedef __attribute__((ext_vector_type(4))) float f32x4;

// problem constants
constexpr int kB = 2, kC = 96, kD = 32, kH = 64, kW = 64;
constexpr int kS = kD * kH * kW;   // 131072 spatial positions per batch
constexpr int kM = kB * kS;        // 262144 total tokens
constexpr int kBW = 4096;          // total windows
constexpr float kScale = 0.17677669529663687f;  // 32^-0.5

DEVI u16 f2bf(float f) {           // fp32 -> bf16 round-to-nearest-even
  u32 x = __float_as_uint(f);
  return (u16)((x + 0x7fffu + ((x >> 16) & 1u)) >> 16);
}
DEVI float bf2f(u16 v) { return __uint_as_float(((u32)v) << 16); }
DEVI u32 pack2(float a, float b) { return (u32)f2bf(a) | ((u32)f2bf(b) << 16); }

// ---------------- transpose (B,C,S) <-> (B,S,C) ----------------
__global__ void k_tin(const float* __restrict__ in, float* __restrict__ out) {
  __shared__ float tile[32][33];
  int s0 = blockIdx.x << 5, c0 = blockIdx.y << 5, b = blockIdx.z;
  int tx = threadIdx.x, ty = threadIdx.y;
#pragma unroll
  for (int q = 0; q < 4; q++)
    tile[ty + q * 8][tx] = in[((size_t)(b * kC + c0 + ty + q * 8)) * kS + s0 + tx];
  __syncthreads();
#pragma unroll
  for (int q = 0; q < 4; q++)
    out[((size_t)(b * kS + s0 + ty + q * 8)) * kC + c0 + tx] = tile[tx][ty + q * 8];
}

__global__ void k_tout(const float* __restrict__ in, float* __restrict__ out) {
  __shared__ float tile[32][33];
  int s0 = blockIdx.x << 5, c0 = blockIdx.y << 5, b = blockIdx.z;
  int tx = threadIdx.x, ty = threadIdx.y;
#pragma unroll
  for (int q = 0; q < 4; q++)
    tile[ty + q * 8][tx] = in[((size_t)(b * kS + s0 + ty + q * 8)) * kC + c0 + tx];
  __syncthreads();
#pragma unroll
  for (int q = 0; q < 4; q++)
    out[((size_t)(b * kC + c0 + ty + q * 8)) * kS + s0 + tx] = tile[tx][ty + q * 8];
}

// ---------------- LayerNorm (one wave per 96-channel row) ----------------
template <int MODE>
__global__ __launch_bounds__(256) void k_ln(const float* __restrict__ x,
                                            const float* __restrict__ g,
                                            const float* __restrict__ bt,
                                            u16* __restrict__ out) {
  int row = (blockIdx.x << 2) + (threadIdx.x >> 6);
  int lane = threadIdx.x & 63;
  int src;
  if (MODE == 0) {
    src = row;
  } else {
    int widx = row >> 6, n = row & 63;
    int ww = widx & 15, wh = (widx >> 4) & 15, wd = (widx >> 8) & 7, bb = widx >> 11;
    int lw = n & 3, lh = (n >> 2) & 3, ld = n >> 4;
    int d = wd * 4 + ld, h = wh * 4 + lh, w = ww * 4 + lw;
    if (MODE == 2) { d = (d + 2) & 31; h = (h + 2) & 63; w = (w + 2) & 63; }
    src = ((bb * kD + d) * kH + h) * kW + w;
  }
  const float* xr = x + (size_t)src * kC;
  float a0 = xr[lane];
  float a1 = (lane < 32) ? xr[64 + lane] : 0.f;
  float sum = a0 + a1;
#pragma unroll
  for (int m = 32; m; m >>= 1) sum += __shfl_xor(sum, m);
  float mean = sum * (1.f / 96.f);
  float d0 = a0 - mean, d1 = (lane < 32) ? a1 - mean : 0.f;
  float vs = d0 * d0 + d1 * d1;
#pragma unroll
  for (int m = 32; m; m >>= 1) vs += __shfl_xor(vs, m);
  float rstd = rsqrtf(vs * (1.f / 96.f) + 1e-5f);
  u16* orow = out + (size_t)row * kC;
  orow[lane] = f2bf(d0 * rstd * g[lane] + bt[lane]);
  if (lane < 32) orow[64 + lane] = f2bf(d1 * rstd * g[64 + lane] + bt[64 + lane]);
}

// ---------------- MFMA GEMM: out[r][j] = sum_k X[r][k]*W[j][k] + b[j] -------
// Block = 128 rows x 96 cols. 4 waves, each 32 rows x 96 cols (2x6 frags).
// X bf16 [M][KTOT]; W fp32 [N][KTOT] (converted to bf16 during LDS staging).
// EPI 0: bf16 store. EPI 1: GELU -> bf16. EPI 2: fp32 += into oadd (residual).
// GATHER 1: X row = window-partition source of natural row r (proj path).
template <int KTOT, int EPI, int GATHER>
__global__ __launch_bounds__(256) void k_mm(const u16* __restrict__ X,
                                            const float* __restrict__ Wm,
                                            const float* __restrict__ bias,
                                            u16* __restrict__ obf,
                                            float* __restrict__ oadd,
                                            int njtot, int shifted) {
  __shared__ __align__(16) u16 Xs[128][104];
  __shared__ __align__(16) u16 Ws[96][104];
  int tid = threadIdx.x;
  int wv = tid >> 6, lane = tid & 63;
  int llo = lane & 15, lhi = lane >> 4;
  int r0 = blockIdx.x << 7;
  int j0 = blockIdx.y * 96;
  f32x4 acc[2][6];
#pragma unroll
  for (int i = 0; i < 2; i++)
#pragma unroll
    for (int j = 0; j < 6; j++) acc[i][j] = (f32x4){0.f, 0.f, 0.f, 0.f};

  for (int kc = 0; kc < KTOT; kc += 96) {
    if (kc) __syncthreads();
    // stage 128x96 activation tile (bf16, row stride padded to 104)
    for (int s = tid; s < 128 * 12; s += 256) {
      int row = s / 12, c8 = s - row * 12;
      int r = r0 + row, rsrc;
      if (GATHER) {
        int w = r & 63, h = (r >> 6) & 63, d = (r >> 12) & 31, bb = r >> 17;
        if (shifted) { d = (d + 30) & 31; h = (h + 62) & 63; w = (w + 62) & 63; }
        int widx = ((bb * 8 + (d >> 2)) * 16 + (h >> 2)) * 16 + (w >> 2);
        rsrc = (widx << 6) + ((d & 3) << 4) + ((h & 3) << 2) + (w & 3);
      } else {
        rsrc = r;
      }
      *(uint4*)&Xs[row][c8 * 8] = *(const uint4*)(X + (size_t)rsrc * KTOT + kc + c8 * 8);
    }
    // stage 96x96 weight tile, fp32 -> bf16
    for (int s = tid; s < 96 * 12; s += 256) {
      int row = s / 12, c8 = s - row * 12;
      const float* src = Wm + (size_t)(j0 + row) * KTOT + kc + c8 * 8;
      float4 w0 = *(const float4*)src, w1 = *(const float4*)(src + 4);
      uint4 pk = {pack2(w0.x, w0.y), pack2(w0.z, w0.w),
                  pack2(w1.x, w1.y), pack2(w1.z, w1.w)};
      *(uint4*)&Ws[row][c8 * 8] = pk;
    }
    __syncthreads();
#pragma unroll
    for (int ks = 0; ks < 3; ks++) {
      bf16x8 a[2], b[6];
#pragma unroll
      for (int i = 0; i < 2; i++)
        a[i] = *(const bf16x8*)&Xs[wv * 32 + i * 16 + llo][ks * 32 + lhi * 8];
#pragma unroll
      for (int j = 0; j < 6; j++)
        b[j] = *(const bf16x8*)&Ws[j * 16 + llo][ks * 32 + lhi * 8];
#pragma unroll
      for (int i = 0; i < 2; i++)
#pragma unroll
        for (int j = 0; j < 6; j++)
          acc[i][j] = __builtin_amdgcn_mfma_f32_16x16x32_bf16(a[i], b[j], acc[i][j], 0, 0, 0);
    }
  }
  // epilogue: D layout col = lane&15, row = (lane>>4)*4 + reg   [m89]
#pragma unroll
  for (int i = 0; i < 2; i++) {
    int rbase = r0 + wv * 32 + i * 16 + lhi * 4;
#pragma unroll
    for (int j = 0; j < 6; j++) {
      int col = j0 + j * 16 + llo;
      float bv = bias[col];
#pragma unroll
      for (int rg = 0; rg < 4; rg++) {
        float v = acc[i][j][rg] + bv;
        int row = rbase + rg;
        if (EPI == 0) {
          obf[(size_t)row * njtot + col] = f2bf(v);
        } else if (EPI == 1) {
          obf[(size_t)row * njtot + col] =
              f2bf(0.5f * v * (1.f + erff(v * 0.70710678118654752f)));
        } else {
          oadd[(size_t)row * 96 + col] += v;
        }
      }
    }
  }
}

// ---------------- MFMA windowed attention: one WAVE per (window, head) ------
// Q,K,V fragments gathered directly from global (full cache-line utilization).
// S = Q.K^T via 16 mfma; softmax in-register (shfl butterfly over llo);
// P staged bf16 in LDS (stride 76 => conflict-free b128 reads); PV = 16 mfma.
__global__ __launch_bounds__(64) void k_attn(const u16* __restrict__ qkv,
                                             const float* __restrict__ rpb,
                                             u16* __restrict__ out, int shifted) {
  __shared__ float rpbs[343];
  __shared__ __align__(16) u16 pl[64][76];
  int widx = blockIdx.x, h = blockIdx.y;
  int lane = threadIdx.x;
  int llo = lane & 15, lhi = lane >> 4;
  for (int t = lane; t < 343; t += 64) rpbs[t] = rpb[t * 3 + h];
  const u16* wq = qkv + (size_t)widx * 64 * 288 + h * 32;

  // Q,K fragments: lane reads row (t*16+llo), k-cols lhi*8..+8  [m92 layout]
  bf16x8 aq[4], bk[4];
#pragma unroll
  for (int t = 0; t < 4; t++) {
    aq[t] = *(const bf16x8*)(wq + (t * 16 + llo) * 288 + lhi * 8);
    bk[t] = *(const bf16x8*)(wq + 96 + (t * 16 + llo) * 288 + lhi * 8);
  }
  // S[qt][kt]: D col = j = kt*16+llo, row = q = qt*16 + lhi*4 + e
  f32x4 s[4][4];
#pragma unroll
  for (int qt = 0; qt < 4; qt++)
#pragma unroll
    for (int kt = 0; kt < 4; kt++)
      s[qt][kt] = __builtin_amdgcn_mfma_f32_16x16x32_bf16(
          aq[qt], bk[kt], (f32x4){0.f, 0.f, 0.f, 0.f}, 0, 0, 0);

  // V fragments (B-operand of PV): lane needs V[k = ks*32+lhi*8+e][d = jt*16+llo]
  // issued now so the latency hides under softmax
  bf16x8 bv[2][2];
#pragma unroll
  for (int jt = 0; jt < 2; jt++)
#pragma unroll
    for (int ks = 0; ks < 2; ks++) {
      bf16x8 t;
#pragma unroll
      for (int e = 0; e < 8; e++)
        t[e] = (short)wq[(size_t)(ks * 32 + lhi * 8 + e) * 288 + 192 + jt * 16 + llo];
      bv[jt][ks] = t;
    }

  // window-local geometry: q = qt*16+lhi*4+e -> (ld,lh,lw)=(qt,lhi,e)
  //                        j = kt*16+llo     -> (jd,jh,jw)=(kt,llo>>2,llo&3)
  int jh = llo >> 2, jw = llo & 3;
  int ww = widx & 15, wh = (widx >> 4) & 15, wd = (widx >> 8) & 7;
  int mi_h = (wh == 15) ? (1 + (lhi >= 2)) : 0;   // q's h mask component
  int mj_hw = ((wh == 15) ? (1 + (jh >= 2)) : 0) * 3 +
              ((ww == 15) ? (1 + (jw >= 2)) : 0); // j's h+w component

  // scale + bias + mask
#pragma unroll
  for (int qt = 0; qt < 4; qt++) {
#pragma unroll
    for (int kt = 0; kt < 4; kt++) {
      const float* rb = &rpbs[(qt - kt + 3) * 49 + (lhi - jh + 3) * 7 + (3 - jw)];
#pragma unroll
      for (int e = 0; e < 4; e++) {
        float val = fmaf(s[qt][kt][e], kScale, rb[e]);
        if (shifted) {
          int ci = ((wd == 7) ? (1 + (qt >= 2)) : 0) * 9 + mi_h * 3 +
                   ((ww == 15) ? (1 + (e >= 2)) : 0);
          int cj = ((wd == 7) ? (1 + (kt >= 2)) : 0) * 9 + mj_hw;
          if (ci != cj) val -= 100.f;
        }
        s[qt][kt][e] = val;
      }
    }
  }

  // softmax per row (qt,e): local max/sum over kt, butterfly over llo lanes
#pragma unroll
  for (int qt = 0; qt < 4; qt++) {
    f32x4 m;
#pragma unroll
    for (int e = 0; e < 4; e++)
      m[e] = fmaxf(fmaxf(s[qt][0][e], s[qt][1][e]), fmaxf(s[qt][2][e], s[qt][3][e]));
#pragma unroll
    for (int msk = 1; msk <= 8; msk <<= 1)
#pragma unroll
      for (int e = 0; e < 4; e++) m[e] = fmaxf(m[e], __shfl_xor(m[e], msk));
    f32x4 sum = (f32x4){0.f, 0.f, 0.f, 0.f};
#pragma unroll
    for (int kt = 0; kt < 4; kt++)
#pragma unroll
      for (int e = 0; e < 4; e++) {
        float p = __expf(s[qt][kt][e] - m[e]);
        s[qt][kt][e] = p;
        sum[e] += p;
      }
#pragma unroll
    for (int msk = 1; msk <= 8; msk <<= 1)
#pragma unroll
      for (int e = 0; e < 4; e++) sum[e] += __shfl_xor(sum[e], msk);
#pragma unroll
    for (int e = 0; e < 4; e++) sum[e] = 1.f / sum[e];
#pragma unroll
    for (int kt = 0; kt < 4; kt++)
#pragma unroll
      for (int e = 0; e < 4; e++)
        pl[qt * 16 + lhi * 4 + e][kt * 16 + llo] = f2bf(s[qt][kt][e] * sum[e]);
  }

  // PV: A = P rows q (2 k-chunks), B = bv (V^T rows d)
  f32x4 o[4][2];
#pragma unroll
  for (int qt = 0; qt < 4; qt++) {
    o[qt][0] = (f32x4){0.f, 0.f, 0.f, 0.f};
    o[qt][1] = (f32x4){0.f, 0.f, 0.f, 0.f};
#pragma unroll
    for (int ks = 0; ks < 2; ks++) {
      bf16x8 pa = *(const bf16x8*)&pl[qt * 16 + llo][ks * 32 + lhi * 8];
      o[qt][0] = __builtin_amdgcn_mfma_f32_16x16x32_bf16(pa, bv[0][ks], o[qt][0], 0, 0, 0);
      o[qt][1] = __builtin_amdgcn_mfma_f32_16x16x32_bf16(pa, bv[1][ks], o[qt][1], 0, 0, 0);
    }
  }

  u16* orow = out + (size_t)widx * 64 * 96 + h * 32;
#pragma unroll
  for (int qt = 0; qt < 4; qt++)
#pragma unroll
    for (int jt = 0; jt < 2; jt++)
#pragma unroll
      for (int e = 0; e < 4; e++)
        orow[(size_t)(qt * 16 + lhi * 4 + e) * 96 + jt * 16 + llo] = f2bf(o[qt][jt][e]);
}

// ---------------- launcher ----------------
extern "C" void kernel_launch(void* const* d_in, const int* in_sizes, int n_in,
                              void* d_out, int out_size, void* d_ws, size_t ws_size,
                              hipStream_t stream) {
  const float* x_in = (const float*)d_in[0];
  const float* n1g = (const float*)d_in[1];
  const float* n1b = (const float*)d_in[2];
  const float* qkvw = (const float*)d_in[3];
  const float* qkvb = (const float*)d_in[4];
  const float* rpb = (const float*)d_in[5];
  const float* projw = (const float*)d_in[6];
  const float* projb = (const float*)d_in[7];
  const float* n2g = (const float*)d_in[8];
  const float* n2b = (const float*)d_in[9];
  const float* fc1w = (const float*)d_in[10];
  const float* fc1b = (const float*)d_in[11];
  const float* fc2w = (const float*)d_in[12];
  const float* fc2b = (const float*)d_in[13];
  float* outp = (float*)d_out;

  // workspace: fp32 master x (100.7 MB) | bf16 small buf (50.3 MB) | bf16 big buf (201.3 MB)
  char* ws = (char*)d_ws;
  float* bx = (float*)ws;
  u16* ba = (u16*)(ws + 100663296);   // xw / attn_out / xn2
  u16* bb = (u16*)(ws + 150994944);   // qkv / mlp hidden

  k_tin<<<dim3(kS / 32, 3, kB), dim3(32, 8), 0, stream>>>(x_in, bx);

  for (int blk = 0; blk < 2; blk++) {
    int sh = blk;  // block 1 is shifted
    if (blk == 0)
      k_ln<1><<<kM / 4, 256, 0, stream>>>(bx, n1g, n1b, ba);
    else
      k_ln<2><<<kM / 4, 256, 0, stream>>>(bx, n1g + 96, n1b + 96, ba);
    k_mm<96, 0, 0><<<dim3(kM / 128, 3), 256, 0, stream>>>(
        ba, qkvw + blk * 288 * 96, qkvb + blk * 288, bb, nullptr, 288, 0);
    k_attn<<<dim3(kBW, 3), 64, 0, stream>>>(bb, rpb + blk * 343 * 3, ba, sh);
    k_mm<96, 2, 1><<<dim3(kM / 128, 1), 256, 0, stream>>>(
        ba, projw + blk * 96 * 96, projb + blk * 96, nullptr, bx, 96, sh);
    k_ln<0><<<kM / 4, 256, 0, stream>>>(bx, n2g + blk * 96, n2b + blk * 96, ba);
    k_mm<96, 1, 0><<<dim3(kM / 128, 4), 256, 0, stream>>>(
        ba, fc1w + blk * 384 * 96, fc1b + blk * 384, bb, nullptr, 384, 0);
    k_mm<384, 2, 0><<<dim3(kM / 128, 1), 256, 0, stream>>>(
        bb, fc2w + blk * 96 * 384, fc2b + blk * 96, nullptr, bx, 96, 0);
  }

  k_tout<<<dim3(kS / 32, 3, kB), dim3(32, 8), 0, stream>>>(bx, outp);
}

// Round 4
// 1054.548 us; speedup vs baseline: 12.4868x; 1.0403x over previous
//
#include <hip/hip_runtime.h>
#include <math.h>

typedef unsigned short u16;
typedef unsigned int u32;
#define DEVI __device__ __forceinline__

typedef __attribute__((ext_vector_type(8))) short bf16x8;
typedef __attribute__((ext_vector_type(4))) float f32x4;

// problem constants
constexpr int kB = 2, kC = 96, kD = 32, kH = 64, kW = 64;
constexpr int kS = kD * kH * kW;   // 131072 spatial positions per batch
constexpr int kM = kB * kS;        // 262144 total tokens
constexpr float kScale = 0.17677669529663687f;  // 32^-0.5

DEVI u16 f2bf(float f) {           // fp32 -> bf16 round-to-nearest-even
  u32 x = __float_as_uint(f);
  return (u16)((x + 0x7fffu + ((x >> 16) & 1u)) >> 16);
}
DEVI float bf2f(u16 v) { return __uint_as_float(((u32)v) << 16); }
DEVI u32 pack2(float a, float b) { return (u32)f2bf(a) | ((u32)f2bf(b) << 16); }

// ---------------- transpose (B,C,S) <-> (B,S,C) ----------------
__global__ void k_tin(const float* __restrict__ in, float* __restrict__ out) {
  __shared__ float tile[32][33];
  int s0 = blockIdx.x << 5, c0 = blockIdx.y << 5, b = blockIdx.z;
  int tx = threadIdx.x, ty = threadIdx.y;
#pragma unroll
  for (int q = 0; q < 4; q++)
    tile[ty + q * 8][tx] = in[((size_t)(b * kC + c0 + ty + q * 8)) * kS + s0 + tx];
  __syncthreads();
#pragma unroll
  for (int q = 0; q < 4; q++)
    out[((size_t)(b * kS + s0 + ty + q * 8)) * kC + c0 + tx] = tile[tx][ty + q * 8];
}

__global__ void k_tout(const float* __restrict__ in, float* __restrict__ out) {
  __shared__ float tile[32][33];
  int s0 = blockIdx.x << 5, c0 = blockIdx.y << 5, b = blockIdx.z;
  int tx = threadIdx.x, ty = threadIdx.y;
#pragma unroll
  for (int q = 0; q < 4; q++)
    tile[ty + q * 8][tx] = in[((size_t)(b * kS + s0 + ty + q * 8)) * kC + c0 + tx];
  __syncthreads();
#pragma unroll
  for (int q = 0; q < 4; q++)
    out[((size_t)(b * kC + c0 + ty + q * 8)) * kS + s0 + tx] = tile[tx][ty + q * 8];
}

// ---------------- LayerNorm (one wave per 96-channel row) ----------------
// MODE 1: window-partition output order. MODE 2: window-partition of rolled tensor.
template <int MODE>
__global__ __launch_bounds__(256) void k_ln(const float* __restrict__ x,
                                            const float* __restrict__ g,
                                            const float* __restrict__ bt,
                                            u16* __restrict__ out) {
  int row = (blockIdx.x << 2) + (threadIdx.x >> 6);
  int lane = threadIdx.x & 63;
  int widx = row >> 6, n = row & 63;
  int ww = widx & 15, wh = (widx >> 4) & 15, wd = (widx >> 8) & 7, bb = widx >> 11;
  int lw = n & 3, lh = (n >> 2) & 3, ld = n >> 4;
  int d = wd * 4 + ld, h = wh * 4 + lh, w = ww * 4 + lw;
  if (MODE == 2) { d = (d + 2) & 31; h = (h + 2) & 63; w = (w + 2) & 63; }
  int src = ((bb * kD + d) * kH + h) * kW + w;
  const float* xr = x + (size_t)src * kC;
  float a0 = xr[lane];
  float a1 = (lane < 32) ? xr[64 + lane] : 0.f;
  float sum = a0 + a1;
#pragma unroll
  for (int m = 32; m; m >>= 1) sum += __shfl_xor(sum, m);
  float mean = sum * (1.f / 96.f);
  float d0 = a0 - mean, d1 = (lane < 32) ? a1 - mean : 0.f;
  float vs = d0 * d0 + d1 * d1;
#pragma unroll
  for (int m = 32; m; m >>= 1) vs += __shfl_xor(vs, m);
  float rstd = rsqrtf(vs * (1.f / 96.f) + 1e-5f);
  u16* orow = out + (size_t)row * kC;
  orow[lane] = f2bf(d0 * rstd * g[lane] + bt[lane]);
  if (lane < 32) orow[64 + lane] = f2bf(d1 * rstd * g[64 + lane] + bt[64 + lane]);
}

// ---------------- MFMA GEMM: out[r][j] = sum_k X[r][k]*W[j][k] + b[j] -------
// Block = 128 rows x 96 cols. 4 waves, each 32 rows x 96 cols (2x6 frags).
// EPI 1: GELU -> bf16. EPI 2: fp32 += into oadd. EPI 3: resid+LN fused:
//   bx[r] += v; then LayerNorm row -> bf16 obf (needs j-grid == 1).
// GATHER 1: X row = window-partition source of natural row r.
template <int KTOT, int EPI, int GATHER>
__global__ __launch_bounds__(256) void k_mm(const u16* __restrict__ X,
                                            const float* __restrict__ Wm,
                                            const float* __restrict__ bias,
                                            u16* __restrict__ obf,
                                            float* __restrict__ oadd,
                                            const float* __restrict__ lng,
                                            const float* __restrict__ lnb,
                                            int njtot, int shifted) {
  __shared__ __align__(16) u16 Xs[128][104];
  __shared__ __align__(16) u16 Ws[96][104];
  int tid = threadIdx.x;
  int wv = tid >> 6, lane = tid & 63;
  int llo = lane & 15, lhi = lane >> 4;
  int r0 = blockIdx.x << 7;
  int j0 = blockIdx.y * 96;
  f32x4 acc[2][6];
#pragma unroll
  for (int i = 0; i < 2; i++)
#pragma unroll
    for (int j = 0; j < 6; j++) acc[i][j] = (f32x4){0.f, 0.f, 0.f, 0.f};

  for (int kc = 0; kc < KTOT; kc += 96) {
    if (kc) __syncthreads();
    for (int s = tid; s < 128 * 12; s += 256) {
      int row = s / 12, c8 = s - row * 12;
      int r = r0 + row, rsrc;
      if (GATHER) {
        int w = r & 63, h = (r >> 6) & 63, d = (r >> 12) & 31, bb = r >> 17;
        if (shifted) { d = (d + 30) & 31; h = (h + 62) & 63; w = (w + 62) & 63; }
        int widx = ((bb * 8 + (d >> 2)) * 16 + (h >> 2)) * 16 + (w >> 2);
        rsrc = (widx << 6) + ((d & 3) << 4) + ((h & 3) << 2) + (w & 3);
      } else {
        rsrc = r;
      }
      *(uint4*)&Xs[row][c8 * 8] = *(const uint4*)(X + (size_t)rsrc * KTOT + kc + c8 * 8);
    }
    for (int s = tid; s < 96 * 12; s += 256) {
      int row = s / 12, c8 = s - row * 12;
      const float* src = Wm + (size_t)(j0 + row) * KTOT + kc + c8 * 8;
      float4 w0 = *(const float4*)src, w1 = *(const float4*)(src + 4);
      uint4 pk = {pack2(w0.x, w0.y), pack2(w0.z, w0.w),
                  pack2(w1.x, w1.y), pack2(w1.z, w1.w)};
      *(uint4*)&Ws[row][c8 * 8] = pk;
    }
    __syncthreads();
#pragma unroll
    for (int ks = 0; ks < 3; ks++) {
      bf16x8 a[2], b[6];
#pragma unroll
      for (int i = 0; i < 2; i++)
        a[i] = *(const bf16x8*)&Xs[wv * 32 + i * 16 + llo][ks * 32 + lhi * 8];
#pragma unroll
      for (int j = 0; j < 6; j++)
        b[j] = *(const bf16x8*)&Ws[j * 16 + llo][ks * 32 + lhi * 8];
#pragma unroll
      for (int i = 0; i < 2; i++)
#pragma unroll
        for (int j = 0; j < 6; j++)
          acc[i][j] = __builtin_amdgcn_mfma_f32_16x16x32_bf16(a[i], b[j], acc[i][j], 0, 0, 0);
    }
  }

  if (EPI == 3) {
    // fused residual + LayerNorm epilogue (j0 == 0, full 96 cols per block)
    float bj[6], gj[6], betaj[6];
#pragma unroll
    for (int j = 0; j < 6; j++) {
      int col = j * 16 + llo;
      bj[j] = bias[col]; gj[j] = lng[col]; betaj[j] = lnb[col];
    }
#pragma unroll
    for (int i = 0; i < 2; i++) {
#pragma unroll
      for (int rg = 0; rg < 4; rg++) {
        int row = r0 + wv * 32 + i * 16 + lhi * 4 + rg;
        float vv[6], sum = 0.f;
#pragma unroll
        for (int j = 0; j < 6; j++) {
          vv[j] = acc[i][j][rg] + bj[j] + oadd[(size_t)row * 96 + j * 16 + llo];
          sum += vv[j];
        }
#pragma unroll
        for (int m = 1; m <= 8; m <<= 1) sum += __shfl_xor(sum, m);
        float mean = sum * (1.f / 96.f);
        float vs = 0.f;
#pragma unroll
        for (int j = 0; j < 6; j++) { float dd = vv[j] - mean; vs += dd * dd; }
#pragma unroll
        for (int m = 1; m <= 8; m <<= 1) vs += __shfl_xor(vs, m);
        float rstd = rsqrtf(vs * (1.f / 96.f) + 1e-5f);
#pragma unroll
        for (int j = 0; j < 6; j++) {
          int col = j * 16 + llo;
          oadd[(size_t)row * 96 + col] = vv[j];
          obf[(size_t)row * 96 + col] = f2bf((vv[j] - mean) * rstd * gj[j] + betaj[j]);
        }
      }
    }
  } else {
#pragma unroll
    for (int i = 0; i < 2; i++) {
      int rbase = r0 + wv * 32 + i * 16 + lhi * 4;
#pragma unroll
      for (int j = 0; j < 6; j++) {
        int col = j0 + j * 16 + llo;
        float bv = bias[col];
#pragma unroll
        for (int rg = 0; rg < 4; rg++) {
          float v = acc[i][j][rg] + bv;
          int row = rbase + rg;
          if (EPI == 1) {
            obf[(size_t)row * njtot + col] =
                f2bf(0.5f * v * (1.f + erff(v * 0.70710678118654752f)));
          } else {
            oadd[(size_t)row * 96 + col] += v;
          }
        }
      }
    }
  }
}

// ---------------- fused QKV-GEMM + windowed attention ----------------------
// One block = 2 windows (128 rows). Phase 1: qkv = X@W^T+b via MFMA, Q/K to
// LDS row-major, V transposed. Phase 2: 12 (window,head,q-half) units over
// 4 waves, in-register softmax (round-3-verified math), PV via MFMA.
__global__ __launch_bounds__(256) void k_qa(const u16* __restrict__ X,
                                            const float* __restrict__ Wq,
                                            const float* __restrict__ bq,
                                            const float* __restrict__ rpb,
                                            u16* __restrict__ out, int shifted) {
  __shared__ __align__(16) char arena[125440];
  u16* Xs = (u16*)arena;                 // [128][104]
  u16* Ws = (u16*)(arena + 26624);       // [96][104]
  u16* QK = (u16*)(arena + 46592);       // [128][200]: cols 0..95 Q, 96..191 K
  u16* VT = (u16*)(arena + 97792);       // [pair][head][32 d][72]: V^T
  u16* PL = (u16*)arena;                 // overlay Xs: [wave][32][72]
  float* RP = (float*)(arena + 18432);   // overlay Xs tail: [3][343]

  int tid = threadIdx.x, wv = tid >> 6, lane = tid & 63;
  int llo = lane & 15, lhi = lane >> 4;
  int r0 = blockIdx.x << 7;

  // stage X (128 rows x 96, window-ordered => contiguous)
  for (int s = tid; s < 128 * 12; s += 256) {
    int row = s / 12, c8 = s - row * 12;
    *(uint4*)&Xs[row * 104 + c8 * 8] = *(const uint4*)(X + (size_t)(r0 + row) * 96 + c8 * 8);
  }

  for (int c = 0; c < 3; c++) {
    // stage W rows c*96..+96 (fp32 -> bf16)
    for (int s = tid; s < 96 * 12; s += 256) {
      int row = s / 12, c8 = s - row * 12;
      const float* src = Wq + (size_t)(c * 96 + row) * 96 + c8 * 8;
      float4 w0 = *(const float4*)src, w1 = *(const float4*)(src + 4);
      uint4 pk = {pack2(w0.x, w0.y), pack2(w0.z, w0.w),
                  pack2(w1.x, w1.y), pack2(w1.z, w1.w)};
      *(uint4*)&Ws[row * 104 + c8 * 8] = pk;
    }
    __syncthreads();
    f32x4 acc[2][6];
#pragma unroll
    for (int i = 0; i < 2; i++)
#pragma unroll
      for (int j = 0; j < 6; j++) acc[i][j] = (f32x4){0.f, 0.f, 0.f, 0.f};
#pragma unroll
    for (int ks = 0; ks < 3; ks++) {
      bf16x8 a[2], b[6];
#pragma unroll
      for (int i = 0; i < 2; i++)
        a[i] = *(const bf16x8*)&Xs[(wv * 32 + i * 16 + llo) * 104 + ks * 32 + lhi * 8];
#pragma unroll
      for (int j = 0; j < 6; j++)
        b[j] = *(const bf16x8*)&Ws[(j * 16 + llo) * 104 + ks * 32 + lhi * 8];
#pragma unroll
      for (int i = 0; i < 2; i++)
#pragma unroll
        for (int j = 0; j < 6; j++)
          acc[i][j] = __builtin_amdgcn_mfma_f32_16x16x32_bf16(a[i], b[j], acc[i][j], 0, 0, 0);
    }
    if (c < 2) {  // Q (c=0) / K (c=1) -> QK row-major
#pragma unroll
      for (int j = 0; j < 6; j++) {
        int col = c * 96 + j * 16 + llo;
        float bb_ = bq[col];
#pragma unroll
        for (int i = 0; i < 2; i++)
#pragma unroll
          for (int rg = 0; rg < 4; rg++)
            QK[(wv * 32 + i * 16 + lhi * 4 + rg) * 200 + col] = f2bf(acc[i][j][rg] + bb_);
      }
    } else {      // V -> VT transposed per (pair, head)
#pragma unroll
      for (int j = 0; j < 6; j++) {
        int dcol = j * 16 + llo;
        float bb_ = bq[192 + dcol];
        int head = dcol >> 5, d = dcol & 31;
#pragma unroll
        for (int i = 0; i < 2; i++)
#pragma unroll
          for (int rg = 0; rg < 4; rg++) {
            int row = wv * 32 + i * 16 + lhi * 4 + rg;
            VT[(((row >> 6) * 3 + head) * 32 + d) * 72 + (row & 63)] =
                f2bf(acc[i][j][rg] + bb_);
          }
      }
    }
    __syncthreads();
  }
  // stage rel-pos bias (Xs now dead; RP region disjoint from PL)
  for (int t = tid; t < 1029; t += 256) {
    int head = t / 343, idx = t - head * 343;
    RP[t] = rpb[idx * 3 + head];
  }
  __syncthreads();

  // attention: 12 units = (pair, head, q-half) over 4 waves
  u16* plw = PL + wv * 32 * 72;
  for (int s2 = 0; s2 < 3; s2++) {
    int u = wv + (s2 << 2);
    int pair = u / 6, rem = u - pair * 6, head = rem >> 1, qh = rem & 1;
    int widx = (blockIdx.x << 1) + pair;
    int ww = widx & 15, wh = (widx >> 4) & 15, wd = (widx >> 8) & 7;
    const float* rp = RP + head * 343;
    const u16* qkw = QK + pair * 64 * 200;

    bf16x8 aq[2], bk[4];
#pragma unroll
    for (int qt2 = 0; qt2 < 2; qt2++)
      aq[qt2] = *(const bf16x8*)&qkw[(qh * 32 + qt2 * 16 + llo) * 200 + head * 32 + lhi * 8];
#pragma unroll
    for (int kt = 0; kt < 4; kt++)
      bk[kt] = *(const bf16x8*)&qkw[(kt * 16 + llo) * 200 + 96 + head * 32 + lhi * 8];

    f32x4 s[2][4];
#pragma unroll
    for (int qt2 = 0; qt2 < 2; qt2++)
#pragma unroll
      for (int kt = 0; kt < 4; kt++)
        s[qt2][kt] = __builtin_amdgcn_mfma_f32_16x16x32_bf16(
            aq[qt2], bk[kt], (f32x4){0.f, 0.f, 0.f, 0.f}, 0, 0, 0);

    int jh = llo >> 2, jw = llo & 3;
    int mi_h = (wh == 15) ? (1 + (lhi >= 2)) : 0;
    int mj_hw = ((wh == 15) ? (1 + (jh >= 2)) : 0) * 3 +
                ((ww == 15) ? (1 + (jw >= 2)) : 0);
#pragma unroll
    for (int qt2 = 0; qt2 < 2; qt2++) {
      int qt = qh * 2 + qt2;
#pragma unroll
      for (int kt = 0; kt < 4; kt++) {
        const float* rb = &rp[(qt - kt + 3) * 49 + (lhi - jh + 3) * 7 + (3 - jw)];
#pragma unroll
        for (int e = 0; e < 4; e++) {
          float val = fmaf(s[qt2][kt][e], kScale, rb[e]);
          if (shifted) {
            int ci = ((wd == 7) ? (1 + (qt >= 2)) : 0) * 9 + mi_h * 3 +
                     ((ww == 15) ? (1 + (e >= 2)) : 0);
            int cj = ((wd == 7) ? (1 + (kt >= 2)) : 0) * 9 + mj_hw;
            if (ci != cj) val -= 100.f;
          }
          s[qt2][kt][e] = val;
        }
      }
    }
    // softmax per row, then P -> PL (bf16)
#pragma unroll
    for (int qt2 = 0; qt2 < 2; qt2++) {
      f32x4 m;
#pragma unroll
      for (int e = 0; e < 4; e++)
        m[e] = fmaxf(fmaxf(s[qt2][0][e], s[qt2][1][e]), fmaxf(s[qt2][2][e], s[qt2][3][e]));
#pragma unroll
      for (int msk = 1; msk <= 8; msk <<= 1)
#pragma unroll
        for (int e = 0; e < 4; e++) m[e] = fmaxf(m[e], __shfl_xor(m[e], msk));
      f32x4 sum = (f32x4){0.f, 0.f, 0.f, 0.f};
#pragma unroll
      for (int kt = 0; kt < 4; kt++)
#pragma unroll
        for (int e = 0; e < 4; e++) {
          float p = __expf(s[qt2][kt][e] - m[e]);
          s[qt2][kt][e] = p;
          sum[e] += p;
        }
#pragma unroll
      for (int msk = 1; msk <= 8; msk <<= 1)
#pragma unroll
        for (int e = 0; e < 4; e++) sum[e] += __shfl_xor(sum[e], msk);
#pragma unroll
      for (int e = 0; e < 4; e++) sum[e] = 1.f / sum[e];
#pragma unroll
      for (int kt = 0; kt < 4; kt++)
#pragma unroll
        for (int e = 0; e < 4; e++)
          plw[(qt2 * 16 + lhi * 4 + e) * 72 + kt * 16 + llo] = f2bf(s[qt2][kt][e] * sum[e]);
    }
    // PV
    const u16* vtb = VT + (pair * 3 + head) * 32 * 72;
    f32x4 o[2][2];
#pragma unroll
    for (int qt2 = 0; qt2 < 2; qt2++) {
      o[qt2][0] = (f32x4){0.f, 0.f, 0.f, 0.f};
      o[qt2][1] = (f32x4){0.f, 0.f, 0.f, 0.f};
    }
#pragma unroll
    for (int ks = 0; ks < 2; ks++) {
      bf16x8 bv0 = *(const bf16x8*)&vtb[llo * 72 + ks * 32 + lhi * 8];
      bf16x8 bv1 = *(const bf16x8*)&vtb[(16 + llo) * 72 + ks * 32 + lhi * 8];
#pragma unroll
      for (int qt2 = 0; qt2 < 2; qt2++) {
        bf16x8 pa = *(const bf16x8*)&plw[(qt2 * 16 + llo) * 72 + ks * 32 + lhi * 8];
        o[qt2][0] = __builtin_amdgcn_mfma_f32_16x16x32_bf16(pa, bv0, o[qt2][0], 0, 0, 0);
        o[qt2][1] = __builtin_amdgcn_mfma_f32_16x16x32_bf16(pa, bv1, o[qt2][1], 0, 0, 0);
      }
    }
    u16* ob = out + (size_t)widx * 64 * 96 + head * 32;
#pragma unroll
    for (int qt2 = 0; qt2 < 2; qt2++)
#pragma unroll
      for (int jt = 0; jt < 2; jt++)
#pragma unroll
        for (int e = 0; e < 4; e++)
          ob[(size_t)(qh * 32 + qt2 * 16 + lhi * 4 + e) * 96 + jt * 16 + llo] =
              f2bf(o[qt2][jt][e]);
  }
}

// ---------------- launcher ----------------
extern "C" void kernel_launch(void* const* d_in, const int* in_sizes, int n_in,
                              void* d_out, int out_size, void* d_ws, size_t ws_size,
                              hipStream_t stream) {
  const float* x_in = (const float*)d_in[0];
  const float* n1g = (const float*)d_in[1];
  const float* n1b = (const float*)d_in[2];
  const float* qkvw = (const float*)d_in[3];
  const float* qkvb = (const float*)d_in[4];
  const float* rpb = (const float*)d_in[5];
  const float* projw = (const float*)d_in[6];
  const float* projb = (const float*)d_in[7];
  const float* n2g = (const float*)d_in[8];
  const float* n2b = (const float*)d_in[9];
  const float* fc1w = (const float*)d_in[10];
  const float* fc1b = (const float*)d_in[11];
  const float* fc2w = (const float*)d_in[12];
  const float* fc2b = (const float*)d_in[13];
  float* outp = (float*)d_out;

  // workspace: fp32 master x (100.7 MB) | bf16 small buf (50.3 MB) | bf16 big buf (201.3 MB)
  char* ws = (char*)d_ws;
  float* bx = (float*)ws;
  u16* ba = (u16*)(ws + 100663296);   // LN outs (window/natural order)
  u16* bb = (u16*)(ws + 150994944);   // attn-out / mlp hidden

  k_tin<<<dim3(kS / 32, 3, kB), dim3(32, 8), 0, stream>>>(x_in, bx);

  for (int blk = 0; blk < 2; blk++) {
    int sh = blk;  // block 1 is shifted
    if (blk == 0)
      k_ln<1><<<kM / 4, 256, 0, stream>>>(bx, n1g, n1b, ba);
    else
      k_ln<2><<<kM / 4, 256, 0, stream>>>(bx, n1g + 96, n1b + 96, ba);
    k_qa<<<kM / 128, 256, 0, stream>>>(ba, qkvw + blk * 288 * 96, qkvb + blk * 288,
                                       rpb + blk * 343 * 3, bb, sh);
    // proj + residual + LN2 fused
    k_mm<96, 3, 1><<<dim3(kM / 128, 1), 256, 0, stream>>>(
        bb, projw + blk * 96 * 96, projb + blk * 96, ba, bx,
        n2g + blk * 96, n2b + blk * 96, 96, sh);
    k_mm<96, 1, 0><<<dim3(kM / 128, 4), 256, 0, stream>>>(
        ba, fc1w + blk * 384 * 96, fc1b + blk * 384, bb, nullptr, nullptr, nullptr, 384, 0);
    k_mm<384, 2, 0><<<dim3(kM / 128, 1), 256, 0, stream>>>(
        bb, fc2w + blk * 96 * 384, fc2b + blk * 96, nullptr, bx, nullptr, nullptr, 96, 0);
  }

  k_tout<<<dim3(kS / 32, 3, kB), dim3(32, 8), 0, stream>>>(bx, outp);
}

// Round 5
// 901.127 us; speedup vs baseline: 14.6127x; 1.1703x over previous
//
#include <hip/hip_runtime.h>
#include <math.h>

typedef unsigned short u16;
typedef unsigned int u32;
#define DEVI __device__ __forceinline__

typedef __attribute__((ext_vector_type(8))) short bf16x8;
typedef __attribute__((ext_vector_type(4))) float f32x4;

// problem constants
constexpr int kB = 2, kC = 96, kD = 32, kH = 64, kW = 64;
constexpr int kS = kD * kH * kW;   // 131072 spatial positions per batch
constexpr int kM = kB * kS;        // 262144 total tokens
constexpr float kScale = 0.17677669529663687f;  // 32^-0.5

DEVI u16 f2bf(float f) {           // fp32 -> bf16 round-to-nearest-even
  u32 x = __float_as_uint(f);
  return (u16)((x + 0x7fffu + ((x >> 16) & 1u)) >> 16);
}
DEVI float bf2f(u16 v) { return __uint_as_float(((u32)v) << 16); }
DEVI u32 pack2(float a, float b) { return (u32)f2bf(a) | ((u32)f2bf(b) << 16); }

// ---------------- transpose (B,C,S) <-> (B,S,C) ----------------
__global__ void k_tin(const float* __restrict__ in, float* __restrict__ out) {
  __shared__ float tile[32][33];
  int s0 = blockIdx.x << 5, c0 = blockIdx.y << 5, b = blockIdx.z;
  int tx = threadIdx.x, ty = threadIdx.y;
#pragma unroll
  for (int q = 0; q < 4; q++)
    tile[ty + q * 8][tx] = in[((size_t)(b * kC + c0 + ty + q * 8)) * kS + s0 + tx];
  __syncthreads();
#pragma unroll
  for (int q = 0; q < 4; q++)
    out[((size_t)(b * kS + s0 + ty + q * 8)) * kC + c0 + tx] = tile[tx][ty + q * 8];
}

__global__ void k_tout(const float* __restrict__ in, float* __restrict__ out) {
  __shared__ float tile[32][33];
  int s0 = blockIdx.x << 5, c0 = blockIdx.y << 5, b = blockIdx.z;
  int tx = threadIdx.x, ty = threadIdx.y;
#pragma unroll
  for (int q = 0; q < 4; q++)
    tile[ty + q * 8][tx] = in[((size_t)(b * kS + s0 + ty + q * 8)) * kC + c0 + tx];
  __syncthreads();
#pragma unroll
  for (int q = 0; q < 4; q++)
    out[((size_t)(b * kC + c0 + ty + q * 8)) * kS + s0 + tx] = tile[tx][ty + q * 8];
}

// ---------------- LayerNorm (one wave per 96-channel row) ----------------
// MODE 1: window-partition output order. MODE 2: window-partition of rolled tensor.
template <int MODE>
__global__ __launch_bounds__(256) void k_ln(const float* __restrict__ x,
                                            const float* __restrict__ g,
                                            const float* __restrict__ bt,
                                            u16* __restrict__ out) {
  int row = (blockIdx.x << 2) + (threadIdx.x >> 6);
  int lane = threadIdx.x & 63;
  int widx = row >> 6, n = row & 63;
  int ww = widx & 15, wh = (widx >> 4) & 15, wd = (widx >> 8) & 7, bb = widx >> 11;
  int lw = n & 3, lh = (n >> 2) & 3, ld = n >> 4;
  int d = wd * 4 + ld, h = wh * 4 + lh, w = ww * 4 + lw;
  if (MODE == 2) { d = (d + 2) & 31; h = (h + 2) & 63; w = (w + 2) & 63; }
  int src = ((bb * kD + d) * kH + h) * kW + w;
  const float* xr = x + (size_t)src * kC;
  float a0 = xr[lane];
  float a1 = (lane < 32) ? xr[64 + lane] : 0.f;
  float sum = a0 + a1;
#pragma unroll
  for (int m = 32; m; m >>= 1) sum += __shfl_xor(sum, m);
  float mean = sum * (1.f / 96.f);
  float d0 = a0 - mean, d1 = (lane < 32) ? a1 - mean : 0.f;
  float vs = d0 * d0 + d1 * d1;
#pragma unroll
  for (int m = 32; m; m >>= 1) vs += __shfl_xor(vs, m);
  float rstd = rsqrtf(vs * (1.f / 96.f) + 1e-5f);
  u16* orow = out + (size_t)row * kC;
  orow[lane] = f2bf(d0 * rstd * g[lane] + bt[lane]);
  if (lane < 32) orow[64 + lane] = f2bf(d1 * rstd * g[64 + lane] + bt[64 + lane]);
}

// ---------------- MFMA GEMM: out[r][j] = sum_k X[r][k]*W[j][k] + b[j] -------
// Block = 128 rows x 96 cols, 4 waves (each 32 rows x 96 cols, 2x6 frags).
// A-fragments load DIRECTLY from global (no X LDS staging -> 19.5 KB LDS,
// 4 blocks/CU). W fp32 staged to LDS as bf16.
// EPI 1: GELU -> bf16. EPI 2: fp32 += into oadd. EPI 3: resid+LN fused.
// GATHER 1: X row = window-partition source of natural row r.
template <int KTOT, int EPI, int GATHER>
__global__ __launch_bounds__(256, 4) void k_mm(const u16* __restrict__ X,
                                               const float* __restrict__ Wm,
                                               const float* __restrict__ bias,
                                               u16* __restrict__ obf,
                                               float* __restrict__ oadd,
                                               const float* __restrict__ lng,
                                               const float* __restrict__ lnb,
                                               int njtot, int shifted) {
  __shared__ __align__(16) u16 Ws[96][104];
  int tid = threadIdx.x;
  int wv = tid >> 6, lane = tid & 63;
  int llo = lane & 15, lhi = lane >> 4;
  int r0 = blockIdx.x << 7;
  int j0 = blockIdx.y * 96;

  // per-lane A row addresses (gathered once)
  size_t arow[2];
#pragma unroll
  for (int i = 0; i < 2; i++) {
    int r = r0 + wv * 32 + i * 16 + llo, rsrc;
    if (GATHER) {
      int w = r & 63, h = (r >> 6) & 63, d = (r >> 12) & 31, bb = r >> 17;
      if (shifted) { d = (d + 30) & 31; h = (h + 62) & 63; w = (w + 62) & 63; }
      int widx = ((bb * 8 + (d >> 2)) * 16 + (h >> 2)) * 16 + (w >> 2);
      rsrc = (widx << 6) + ((d & 3) << 4) + ((h & 3) << 2) + (w & 3);
    } else {
      rsrc = r;
    }
    arow[i] = (size_t)rsrc * KTOT;
  }

  f32x4 acc[2][6];
#pragma unroll
  for (int i = 0; i < 2; i++)
#pragma unroll
    for (int j = 0; j < 6; j++) acc[i][j] = (f32x4){0.f, 0.f, 0.f, 0.f};

  for (int kc = 0; kc < KTOT; kc += 96) {
    // issue A loads first so they fly under W staging
    bf16x8 a[2][3];
#pragma unroll
    for (int i = 0; i < 2; i++)
#pragma unroll
      for (int ks = 0; ks < 3; ks++)
        a[i][ks] = *(const bf16x8*)(X + arow[i] + kc + ks * 32 + lhi * 8);
    if (kc) __syncthreads();
    for (int s = tid; s < 96 * 12; s += 256) {
      int row = s / 12, c8 = s - row * 12;
      const float* src = Wm + (size_t)(j0 + row) * KTOT + kc + c8 * 8;
      float4 w0 = *(const float4*)src, w1 = *(const float4*)(src + 4);
      uint4 pk = {pack2(w0.x, w0.y), pack2(w0.z, w0.w),
                  pack2(w1.x, w1.y), pack2(w1.z, w1.w)};
      *(uint4*)&Ws[row][c8 * 8] = pk;
    }
    __syncthreads();
#pragma unroll
    for (int ks = 0; ks < 3; ks++) {
      bf16x8 b[6];
#pragma unroll
      for (int j = 0; j < 6; j++)
        b[j] = *(const bf16x8*)&Ws[j * 16 + llo][ks * 32 + lhi * 8];
#pragma unroll
      for (int i = 0; i < 2; i++)
#pragma unroll
        for (int j = 0; j < 6; j++)
          acc[i][j] = __builtin_amdgcn_mfma_f32_16x16x32_bf16(a[i][ks], b[j], acc[i][j], 0, 0, 0);
    }
  }

  if (EPI == 3) {
    // fused residual + LayerNorm epilogue (j0 == 0, full 96 cols per block)
    float bj[6], gj[6], betaj[6];
#pragma unroll
    for (int j = 0; j < 6; j++) {
      int col = j * 16 + llo;
      bj[j] = bias[col]; gj[j] = lng[col]; betaj[j] = lnb[col];
    }
#pragma unroll
    for (int i = 0; i < 2; i++) {
#pragma unroll
      for (int rg = 0; rg < 4; rg++) {
        int row = r0 + wv * 32 + i * 16 + lhi * 4 + rg;
        float vv[6], sum = 0.f;
#pragma unroll
        for (int j = 0; j < 6; j++) {
          vv[j] = acc[i][j][rg] + bj[j] + oadd[(size_t)row * 96 + j * 16 + llo];
          sum += vv[j];
        }
#pragma unroll
        for (int m = 1; m <= 8; m <<= 1) sum += __shfl_xor(sum, m);
        float mean = sum * (1.f / 96.f);
        float vs = 0.f;
#pragma unroll
        for (int j = 0; j < 6; j++) { float dd = vv[j] - mean; vs += dd * dd; }
#pragma unroll
        for (int m = 1; m <= 8; m <<= 1) vs += __shfl_xor(vs, m);
        float rstd = rsqrtf(vs * (1.f / 96.f) + 1e-5f);
#pragma unroll
        for (int j = 0; j < 6; j++) {
          int col = j * 16 + llo;
          oadd[(size_t)row * 96 + col] = vv[j];
          obf[(size_t)row * 96 + col] = f2bf((vv[j] - mean) * rstd * gj[j] + betaj[j]);
        }
      }
    }
  } else {
#pragma unroll
    for (int i = 0; i < 2; i++) {
      int rbase = r0 + wv * 32 + i * 16 + lhi * 4;
#pragma unroll
      for (int j = 0; j < 6; j++) {
        int col = j0 + j * 16 + llo;
        float bv = bias[col];
#pragma unroll
        for (int rg = 0; rg < 4; rg++) {
          float v = acc[i][j][rg] + bv;
          int row = rbase + rg;
          if (EPI == 1) {
            obf[(size_t)row * njtot + col] =
                f2bf(0.5f * v * (1.f + erff(v * 0.70710678118654752f)));
          } else {
            oadd[(size_t)row * 96 + col] += v;
          }
        }
      }
    }
  }
}

// ---------------- fused QKV-GEMM + windowed attention (16 waves) -----------
// One block = 2 windows (128 rows), 1024 threads. GEMM: wave = 16 rows x 48
// cols, A-frags direct from global. Q/K -> LDS row-major; V -> LDS transposed.
// Attention: 12 units (pair,head,qhalf) on waves 0..11; P overlays dead QK.
__global__ __launch_bounds__(1024, 4) void k_qa(const u16* __restrict__ X,
                                                const float* __restrict__ Wq,
                                                const float* __restrict__ bq,
                                                const float* __restrict__ rpb,
                                                u16* __restrict__ out, int shifted) {
  __shared__ __align__(16) char arena[90656];
  u16* QK = (u16*)arena;                 // [128][200]: cols 0..95 Q, 96..191 K
  u16* VT = (u16*)(arena + 51200);       // [pair*3+head][32 d][40]: V^T
  u16* Ws = (u16*)(arena + 66560);       // [96][104]
  float* RP = (float*)(arena + 86528);   // [3][343]

  int tid = threadIdx.x, wv = tid >> 6, lane = tid & 63;
  int llo = lane & 15, lhi = lane >> 4;
  int r0 = blockIdx.x << 7;
  int rowb = (wv >> 1) * 16;             // GEMM row base
  int colb = (wv & 1) * 48;              // GEMM col base

  // rel-pos bias table (region independent of GEMM buffers)
  for (int t = tid; t < 1029; t += 1024) {
    int head = t / 343, idx = t - head * 343;
    RP[t] = rpb[idx * 3 + head];
  }

  // A-fragments for this lane's 16 GEMM rows (shared across Q/K/V chunks)
  const u16* xrow = X + (size_t)(r0 + rowb + llo) * 96;
  bf16x8 a[3];
#pragma unroll
  for (int ks = 0; ks < 3; ks++) a[ks] = *(const bf16x8*)(xrow + ks * 32 + lhi * 8);

  for (int c = 0; c < 3; c++) {
    if (c) __syncthreads();
    for (int s = tid; s < 96 * 12; s += 1024) {
      int row = s / 12, c8 = s - row * 12;
      const float* src = Wq + (size_t)(c * 96 + row) * 96 + c8 * 8;
      float4 w0 = *(const float4*)src, w1 = *(const float4*)(src + 4);
      uint4 pk = {pack2(w0.x, w0.y), pack2(w0.z, w0.w),
                  pack2(w1.x, w1.y), pack2(w1.z, w1.w)};
      *(uint4*)&Ws[row * 104 + c8 * 8] = pk;
    }
    __syncthreads();
    f32x4 acc[3];
#pragma unroll
    for (int j = 0; j < 3; j++) acc[j] = (f32x4){0.f, 0.f, 0.f, 0.f};
#pragma unroll
    for (int ks = 0; ks < 3; ks++) {
#pragma unroll
      for (int j = 0; j < 3; j++) {
        bf16x8 b = *(const bf16x8*)&Ws[(colb + j * 16 + llo) * 104 + ks * 32 + lhi * 8];
        acc[j] = __builtin_amdgcn_mfma_f32_16x16x32_bf16(a[ks], b, acc[j], 0, 0, 0);
      }
    }
    if (c < 2) {  // Q / K -> QK row-major
#pragma unroll
      for (int j = 0; j < 3; j++) {
        int col = colb + j * 16 + llo;
        float bb_ = bq[c * 96 + col];
#pragma unroll
        for (int rg = 0; rg < 4; rg++)
          QK[(rowb + lhi * 4 + rg) * 200 + c * 96 + col] = f2bf(acc[j][rg] + bb_);
      }
    } else {      // V -> VT transposed per (pair, head)
#pragma unroll
      for (int j = 0; j < 3; j++) {
        int dcol = colb + j * 16 + llo;
        float bb_ = bq[192 + dcol];
        int head = dcol >> 5, d = dcol & 31;
#pragma unroll
        for (int rg = 0; rg < 4; rg++) {
          int row = rowb + lhi * 4 + rg;
          VT[(((row >> 6) * 3 + head) * 32 + d) * 40 + (row & 63)] = f2bf(acc[j][rg] + bb_);
        }
      }
    }
  }
  __syncthreads();

  // attention: 12 units = (pair, head, q-half); waves 12..15 idle
  int u = wv;
  bool active = (u < 12);
  int pair = u / 6, rem = u - pair * 6, head = rem >> 1, qh = rem & 1;
  int widx = (blockIdx.x << 1) + pair;
  int ww = widx & 15, wh = (widx >> 4) & 15, wd = (widx >> 8) & 7;
  const float* rp = RP + head * 343;
  const u16* qkw = QK + pair * 64 * 200;
  u16* plw = QK + u * 2112;              // P overlay on dead QK (32 x stride 66)

  f32x4 s[2][4];
  bf16x8 bv[2][2];
  if (active) {
    bf16x8 aq[2], bk[4];
#pragma unroll
    for (int qt2 = 0; qt2 < 2; qt2++)
      aq[qt2] = *(const bf16x8*)&qkw[(qh * 32 + qt2 * 16 + llo) * 200 + head * 32 + lhi * 8];
#pragma unroll
    for (int kt = 0; kt < 4; kt++)
      bk[kt] = *(const bf16x8*)&qkw[(kt * 16 + llo) * 200 + 96 + head * 32 + lhi * 8];
    // V fragments (VT region is not overlaid; load now to hide latency)
    const u16* vtb = VT + (pair * 3 + head) * 32 * 40;
#pragma unroll
    for (int jt = 0; jt < 2; jt++)
#pragma unroll
      for (int ks = 0; ks < 2; ks++)
        bv[jt][ks] = *(const bf16x8*)&vtb[(jt * 16 + llo) * 40 + ks * 32 + lhi * 8];

#pragma unroll
    for (int qt2 = 0; qt2 < 2; qt2++)
#pragma unroll
      for (int kt = 0; kt < 4; kt++)
        s[qt2][kt] = __builtin_amdgcn_mfma_f32_16x16x32_bf16(
            aq[qt2], bk[kt], (f32x4){0.f, 0.f, 0.f, 0.f}, 0, 0, 0);

    int jh = llo >> 2, jw = llo & 3;
    int mi_h = (wh == 15) ? (1 + (lhi >= 2)) : 0;
    int mj_hw = ((wh == 15) ? (1 + (jh >= 2)) : 0) * 3 +
                ((ww == 15) ? (1 + (jw >= 2)) : 0);
#pragma unroll
    for (int qt2 = 0; qt2 < 2; qt2++) {
      int qt = qh * 2 + qt2;
#pragma unroll
      for (int kt = 0; kt < 4; kt++) {
        const float* rb = &rp[(qt - kt + 3) * 49 + (lhi - jh + 3) * 7 + (3 - jw)];
#pragma unroll
        for (int e = 0; e < 4; e++) {
          float val = fmaf(s[qt2][kt][e], kScale, rb[e]);
          if (shifted) {
            int ci = ((wd == 7) ? (1 + (qt >= 2)) : 0) * 9 + mi_h * 3 +
                     ((ww == 15) ? (1 + (e >= 2)) : 0);
            int cj = ((wd == 7) ? (1 + (kt >= 2)) : 0) * 9 + mj_hw;
            if (ci != cj) val -= 100.f;
          }
          s[qt2][kt][e] = val;
        }
      }
    }
    // softmax per row (qt2, e): local max/sum over kt, butterfly over llo
#pragma unroll
    for (int qt2 = 0; qt2 < 2; qt2++) {
      f32x4 m;
#pragma unroll
      for (int e = 0; e < 4; e++)
        m[e] = fmaxf(fmaxf(s[qt2][0][e], s[qt2][1][e]), fmaxf(s[qt2][2][e], s[qt2][3][e]));
#pragma unroll
      for (int msk = 1; msk <= 8; msk <<= 1)
#pragma unroll
        for (int e = 0; e < 4; e++) m[e] = fmaxf(m[e], __shfl_xor(m[e], msk));
      f32x4 sum = (f32x4){0.f, 0.f, 0.f, 0.f};
#pragma unroll
      for (int kt = 0; kt < 4; kt++)
#pragma unroll
        for (int e = 0; e < 4; e++) {
          float p = __expf(s[qt2][kt][e] - m[e]);
          s[qt2][kt][e] = p;
          sum[e] += p;
        }
#pragma unroll
      for (int msk = 1; msk <= 8; msk <<= 1)
#pragma unroll
        for (int e = 0; e < 4; e++) sum[e] += __shfl_xor(sum[e], msk);
#pragma unroll
      for (int e = 0; e < 4; e++) sum[e] = 1.f / sum[e];
#pragma unroll
      for (int kt = 0; kt < 4; kt++)
#pragma unroll
        for (int e = 0; e < 4; e++) s[qt2][kt][e] *= sum[e];
    }
  }
  __syncthreads();  // all QK reads complete -> safe to overlay P
  if (active) {
#pragma unroll
    for (int qt2 = 0; qt2 < 2; qt2++)
#pragma unroll
      for (int kt = 0; kt < 4; kt++)
#pragma unroll
        for (int e = 0; e < 4; e++)
          plw[(qt2 * 16 + lhi * 4 + e) * 66 + kt * 16 + llo] = f2bf(s[qt2][kt][e]);
  }
  __syncthreads();
  if (active) {
    f32x4 o[2][2];
#pragma unroll
    for (int qt2 = 0; qt2 < 2; qt2++) {
      o[qt2][0] = (f32x4){0.f, 0.f, 0.f, 0.f};
      o[qt2][1] = (f32x4){0.f, 0.f, 0.f, 0.f};
#pragma unroll
      for (int ks = 0; ks < 2; ks++) {
        bf16x8 pa = *(const bf16x8*)&plw[(qt2 * 16 + llo) * 66 + ks * 32 + lhi * 8];
        o[qt2][0] = __builtin_amdgcn_mfma_f32_16x16x32_bf16(pa, bv[0][ks], o[qt2][0], 0, 0, 0);
        o[qt2][1] = __builtin_amdgcn_mfma_f32_16x16x32_bf16(pa, bv[1][ks], o[qt2][1], 0, 0, 0);
      }
    }
    u16* ob = out + (size_t)widx * 64 * 96 + head * 32;
#pragma unroll
    for (int qt2 = 0; qt2 < 2; qt2++)
#pragma unroll
      for (int jt = 0; jt < 2; jt++)
#pragma unroll
        for (int e = 0; e < 4; e++)
          ob[(size_t)(qh * 32 + qt2 * 16 + lhi * 4 + e) * 96 + jt * 16 + llo] =
              f2bf(o[qt2][jt][e]);
  }
}

// ---------------- launcher ----------------
extern "C" void kernel_launch(void* const* d_in, const int* in_sizes, int n_in,
                              void* d_out, int out_size, void* d_ws, size_t ws_size,
                              hipStream_t stream) {
  const float* x_in = (const float*)d_in[0];
  const float* n1g = (const float*)d_in[1];
  const float* n1b = (const float*)d_in[2];
  const float* qkvw = (const float*)d_in[3];
  const float* qkvb = (const float*)d_in[4];
  const float* rpb = (const float*)d_in[5];
  const float* projw = (const float*)d_in[6];
  const float* projb = (const float*)d_in[7];
  const float* n2g = (const float*)d_in[8];
  const float* n2b = (const float*)d_in[9];
  const float* fc1w = (const float*)d_in[10];
  const float* fc1b = (const float*)d_in[11];
  const float* fc2w = (const float*)d_in[12];
  const float* fc2b = (const float*)d_in[13];
  float* outp = (float*)d_out;

  // workspace: fp32 master x (100.7 MB) | bf16 small buf (50.3 MB) | bf16 big buf (201.3 MB)
  char* ws = (char*)d_ws;
  float* bx = (float*)ws;
  u16* ba = (u16*)(ws + 100663296);   // LN outs (window order)
  u16* bb = (u16*)(ws + 150994944);   // attn-out / mlp hidden

  k_tin<<<dim3(kS / 32, 3, kB), dim3(32, 8), 0, stream>>>(x_in, bx);

  for (int blk = 0; blk < 2; blk++) {
    int sh = blk;  // block 1 is shifted
    if (blk == 0)
      k_ln<1><<<kM / 4, 256, 0, stream>>>(bx, n1g, n1b, ba);
    else
      k_ln<2><<<kM / 4, 256, 0, stream>>>(bx, n1g + 96, n1b + 96, ba);
    k_qa<<<kM / 128, 1024, 0, stream>>>(ba, qkvw + blk * 288 * 96, qkvb + blk * 288,
                                        rpb + blk * 343 * 3, bb, sh);
    // proj + residual + LN2 fused
    k_mm<96, 3, 1><<<dim3(kM / 128, 1), 256, 0, stream>>>(
        bb, projw + blk * 96 * 96, projb + blk * 96, ba, bx,
        n2g + blk * 96, n2b + blk * 96, 96, sh);
    k_mm<96, 1, 0><<<dim3(kM / 128, 4), 256, 0, stream>>>(
        ba, fc1w + blk * 384 * 96, fc1b + blk * 384, bb, nullptr, nullptr, nullptr, 384, 0);
    k_mm<384, 2, 0><<<dim3(kM / 128, 1), 256, 0, stream>>>(
        bb, fc2w + blk * 96 * 384, fc2b + blk * 96, nullptr, bx, nullptr, nullptr, 96, 0);
  }

  k_tout<<<dim3(kS / 32, 3, kB), dim3(32, 8), 0, stream>>>(bx, outp);
}